// Round 8
// baseline (322.120 us; speedup 1.0000x reference)
//
#include <hip/hip_runtime.h>
#include <hip/hip_bf16.h>
#include <stdint.h>

// SSMBlock: x -> silu(x Wg^T) -> s = xg Wsp^T -> scan(decay) -> out = states WcT^T + xg W2^T + b_out
// R7 GEMM "gemm_wres": persistent blocks. W-panel (64 cols x full K) staged ONCE in LDS
// (64 KB; DUAL: both W panels, 128 KB). Block loops SPM m-stripes of 64 rows; A is
// burst-loaded (16 independent 16B loads/wave) into a static ping-pong reg pair, with
// the next stripe's burst issued BEFORE this stripe's compute -> prefetch distance =
// one full stripe. NO barriers in the steady loop.

typedef __bf16 bf16_t;
typedef bf16_t bf16x8 __attribute__((ext_vector_type(8)));
typedef bf16_t bf16x4 __attribute__((ext_vector_type(4)));
typedef float  f32x4  __attribute__((ext_vector_type(4)));

static __device__ __forceinline__ void async_copy16(bf16_t* lds, const bf16_t* g) {
    __builtin_amdgcn_global_load_lds((const __attribute__((address_space(1))) void*)g,
                                     (__attribute__((address_space(3))) void*)lds, 16, 0, 0);
}

static __device__ __forceinline__ void loadA16(const bf16_t* __restrict__ p, bf16x8 (&a)[16]) {
    #pragma unroll
    for (int ks = 0; ks < 16; ++ks) a[ks] = *(const bf16x8*)(p + ks * 32);
}

static __device__ __forceinline__ void mfma16(const bf16_t* __restrict__ Bs,
                                              bf16x8 (&a)[16], f32x4 (&acc)[4],
                                              int kb, int kc, int lr) {
    #pragma unroll
    for (int ks = 0; ks < 16; ++ks) {
        bf16x8 b[4];
        #pragma unroll
        for (int j = 0; j < 4; ++j)
            b[j] = *(const bf16x8*)(&Bs[((kb + ks * 4 + kc) * 64 + j * 16 + lr) * 8]);
        #pragma unroll
        for (int j = 0; j < 4; ++j)
            acc[j] = __builtin_amdgcn_mfma_f32_16x16x32_bf16(a[ks], b[j], acc[j], 0, 0, 0);
    }
}

// Block 256 thr / 4 waves; wave w owns rows (stripe_m0 + w*16 .. +16), all 64 cols of
// its n-panel. LDS Bs [kcomb][col 64][8]: staged via global_load_lds (dest linear in
// lane order); ds_read_b128 per 16-lane group = contiguous 256B -> 0 bank conflicts
// (verified R0-R6). n-panel = bid&7 -> XCD round-robin keeps one W panel per XCD L2.
// MODE: 0 = f32 out (+bias), 1 = bf16 out (+bias), 2 = silu -> bf16 (+bias)
template <int MODE, bool DUAL>
__global__ __launch_bounds__(256, DUAL ? 1 : 2) void gemm_wres(
    const bf16_t* __restrict__ A0, const bf16_t* __restrict__ W0,
    const bf16_t* __restrict__ A1, const bf16_t* __restrict__ W1,
    const float* __restrict__ bias, void* __restrict__ outp,
    int M, int SPM)
{
    constexpr int K = 512;
    constexpr int KC = DUAL ? 128 : 64;        // kcomb rows in LDS
    __shared__ bf16_t Bs[KC * 64 * 8];         // 64 KB (single) / 128 KB (dual)
    const int tid = threadIdx.x;
    const int bid = blockIdx.x;
    const int n0 = (bid & 7) << 6;             // n-panel -> XCD alignment
    const int mg = bid >> 3;
    const int l = tid & 63, w = tid >> 6;
    const int lr = l & 15, kc = l >> 4;

    // ---- stage W panel(s) once ----
    #pragma unroll
    for (int j = 0; j < 16; ++j)
        async_copy16(&Bs[(j * 256 + w * 64) * 8],
                     W0 + (size_t)(n0 + l) * K + (j * 4 + w) * 8);
    if (DUAL) {
        #pragma unroll
        for (int j = 0; j < 16; ++j)
            async_copy16(&Bs[(64 * 64 + j * 256 + w * 64) * 8],
                         W1 + (size_t)(n0 + l) * K + (j * 4 + w) * 8);
    }

    float bv[4];
    #pragma unroll
    for (int j = 0; j < 4; ++j)
        bv[j] = bias ? bias[n0 + j * 16 + lr] : 0.f;

    float*  outF = (float*)outp;
    bf16_t* outB = (bf16_t*)outp;
    const int m00 = mg * SPM * 64;
    const size_t aoff = (size_t)(w * 16 + lr) * K + kc * 8;
    const size_t astride = (size_t)64 * K;

    __syncthreads();                            // W panel(s) ready (drains gll)

    // epilogue writer for stripe sp
    auto epi = [&](f32x4 (&acc)[4], int sp) {
        const int row = m00 + sp * 64 + w * 16 + kc * 4;
        #pragma unroll
        for (int j = 0; j < 4; ++j) {
            const int col = n0 + j * 16 + lr;
            #pragma unroll
            for (int r = 0; r < 4; ++r) {
                float v = acc[j][r] + bv[j];
                size_t idx = (size_t)(row + r) * 512 + col;
                if (MODE == 0)      outF[idx] = v;
                else if (MODE == 1) outB[idx] = (bf16_t)v;
                else { outB[idx] = (bf16_t)(v / (1.f + __expf(-v))); }
            }
        }
    };

    const f32x4 z = {0.f, 0.f, 0.f, 0.f};
    bf16x8 aA[16], aB[16];

    if (!DUAL) {
        // ping-pong over stripes: prefetch sp+1 before computing sp
        loadA16(A0 + aoff + (size_t)m00 * K, aA);
        for (int sp = 0; sp < SPM; sp += 2) {
            if (sp + 1 < SPM)
                loadA16(A0 + aoff + (size_t)m00 * K + (sp + 1) * astride, aB);
            f32x4 acc[4] = {z, z, z, z};
            mfma16(Bs, aA, acc, 0, kc, lr);
            epi(acc, sp);
            if (sp + 1 < SPM) {
                if (sp + 2 < SPM)
                    loadA16(A0 + aoff + (size_t)m00 * K + (sp + 2) * astride, aA);
                f32x4 acc2[4] = {z, z, z, z};
                mfma16(Bs, aB, acc2, 0, kc, lr);
                epi(acc2, sp + 1);
            }
        }
    } else {
        // per stripe: half0 = A0 x W0 (kb 0), half1 = A1 x W1 (kb 64), one epilogue
        loadA16(A0 + aoff + (size_t)m00 * K, aA);
        for (int sp = 0; sp < SPM; ++sp) {
            loadA16(A1 + aoff + (size_t)m00 * K + sp * astride, aB);   // half1 prefetch
            f32x4 acc[4] = {z, z, z, z};
            mfma16(Bs, aA, acc, 0, kc, lr);
            if (sp + 1 < SPM)                                          // next half0
                loadA16(A0 + aoff + (size_t)m00 * K + (sp + 1) * astride, aA);
            mfma16(Bs, aB, acc, 64, kc, lr);
            epi(acc, sp);
        }
    }
}

// fused prep: x->bf16 (all 8192 blocks), weight prep (blocks<1024), decay (blocks<128)
__global__ void prep_all(const float4* __restrict__ x, bf16x4* __restrict__ xb,
                         const float* __restrict__ Wg, const float* __restrict__ Wsp,
                         const float* __restrict__ Wo, const float* __restrict__ Dp,
                         bf16_t* __restrict__ Wg_bf, bf16_t* __restrict__ Wsp_bf,
                         bf16_t* __restrict__ Wo_bf, bf16_t* __restrict__ W2_bf,
                         const float* __restrict__ A_log, float* __restrict__ decay)
{
    const int blk = blockIdx.x, tid = threadIdx.x;
    {   // x -> bf16, 4 floats/thread
        int i = blk * 256 + tid;
        float4 v = x[i];
        bf16x4 o;
        o[0] = (bf16_t)v.x; o[1] = (bf16_t)v.y; o[2] = (bf16_t)v.z; o[3] = (bf16_t)v.w;
        xb[i] = o;
    }
    if (blk < 1024) {
        int i = blk * 256 + tid;          // 512*512 elements
        Wg_bf[i]  = (bf16_t)Wg[i];
        Wsp_bf[i] = (bf16_t)Wsp[i];
        float wo  = Wo[i];
        Wo_bf[i]  = (bf16_t)wo;
        W2_bf[i]  = (bf16_t)(wo * Dp[i & 511]);   // W2[d',d] = W_out[d',d]*D[d]
    }
    if (blk < 128) {
        int d = blk * 4 + (tid >> 6);     // one wave per row of A_log
        int ll = tid & 63;
        const float* row = A_log + (size_t)d * 512;
        float s = 0.f;
        for (int k = ll; k < 512; k += 64) s += expf(row[k]);
        #pragma unroll
        for (int off = 32; off > 0; off >>= 1) s += __shfl_down(s, off);
        if (ll == 0) decay[d] = expf(-s * (1.f / 512.f));  // exp(mean(-exp(A_log)))
    }
}

// ---- chunked scan: S=4096 -> 64 chunks x 64 steps, per (b,n) lane ----
__global__ void scan_partial(const bf16_t* __restrict__ s, const float* __restrict__ decay,
                             float* __restrict__ carry)
{
    int g = blockIdx.x * 256 + threadIdx.x;       // B*N*64 = 131072
    int n = g & 511, ch = (g >> 9) & 63, b = g >> 15;
    float dec = decay[n];
    const bf16_t* sp = s + (size_t)(b * 4096 + ch * 64) * 512 + n;
    float st = 0.f;
    #pragma unroll 8
    for (int i = 0; i < 64; ++i) st = st * dec + (float)sp[(size_t)i * 512];
    carry[(size_t)(b * 64 + ch) * 512 + n] = st;
}

__global__ void scan_carry(const float* __restrict__ carry, const float* __restrict__ decay,
                           const float* __restrict__ state0,
                           float* __restrict__ exc, float* __restrict__ state_f)
{
    int g = blockIdx.x * 256 + threadIdx.x;       // B*N = 2048
    int n = g & 511, b = g >> 9;
    float dec = decay[n];
    float d64 = dec;
    #pragma unroll
    for (int t = 0; t < 6; ++t) d64 *= d64;       // dec^64 via squaring
    float st = state0[g];
    for (int ch = 0; ch < 64; ++ch) {
        size_t idx = (size_t)(b * 64 + ch) * 512 + n;
        exc[idx] = st;                             // exclusive carry-in per chunk
        st = st * d64 + carry[idx];
    }
    state_f[g] = st;                               // final state -> d_out tail
}

__global__ void scan_final(const bf16_t* __restrict__ s, const float* __restrict__ decay,
                           const float* __restrict__ exc, bf16_t* __restrict__ states)
{
    int g = blockIdx.x * 256 + threadIdx.x;       // B*N*64
    int n = g & 511, ch = (g >> 9) & 63, b = g >> 15;
    float dec = decay[n];
    float st = exc[(size_t)(b * 64 + ch) * 512 + n];
    size_t base = (size_t)(b * 4096 + ch * 64) * 512 + n;
    #pragma unroll 8
    for (int i = 0; i < 64; ++i) {
        st = st * dec + (float)s[base + (size_t)i * 512];
        states[base + (size_t)i * 512] = (bf16_t)st;
    }
}

extern "C" void kernel_launch(void* const* d_in, const int* in_sizes, int n_in,
                              void* d_out, int out_size, void* d_ws, size_t ws_size,
                              hipStream_t stream)
{
    const float* x      = (const float*)d_in[0];
    const float* state0 = (const float*)d_in[1];
    const float* W_gate = (const float*)d_in[2];
    const float* b_gate = (const float*)d_in[3];
    const float* W_sp   = (const float*)d_in[4];
    const float* b_sp   = (const float*)d_in[5];
    const float* W_out  = (const float*)d_in[6];
    const float* b_out  = (const float*)d_in[7];
    const float* A_log  = (const float*)d_in[8];
    const float* D_par  = (const float*)d_in[9];
    float* out = (float*)d_out;

    // workspace layout (~51.5 MB)
    char* ws = (char*)d_ws;
    bf16_t* x_bf   = (bf16_t*)ws;                     // 16 MB, reused for states
    bf16_t* states = x_bf;
    bf16_t* xg_bf  = (bf16_t*)(ws + (16u << 20));     // 16 MB
    bf16_t* s_bf   = (bf16_t*)(ws + (32u << 20));     // 16 MB
    bf16_t* Wg_bf  = (bf16_t*)(ws + (48u << 20));     // 5 x 512 KB weights
    bf16_t* Wsp_bf = Wg_bf + 262144;
    bf16_t* Wo_bf  = Wg_bf + 2 * 262144;
    bf16_t* W2_bf  = Wg_bf + 3 * 262144;
    bf16_t* WcT_bf = Wg_bf + 4 * 262144;
    float*  carry  = (float*)(Wg_bf + 5 * 262144);    // 512 KB
    float*  exc    = carry + 131072;                  // 512 KB
    float*  decay  = exc + 131072;                    // 2 KB

    prep_all<<<dim3(8192), dim3(256), 0, stream>>>(
        (const float4*)x, (bf16x4*)x_bf, W_gate, W_sp, W_out, D_par,
        Wg_bf, Wsp_bf, Wo_bf, W2_bf, A_log, decay);

    // WcT[d',n] = sum_d W_out[d',d] * W_sp[n,d]   (M=512: grid 8 panels x 8 mg, SPM=1)
    gemm_wres<1, false><<<dim3(64), dim3(256), 0, stream>>>(
        Wo_bf, Wsp_bf, (const bf16_t*)nullptr, (const bf16_t*)nullptr,
        (const float*)nullptr, (void*)WcT_bf, 512, 1);
    // xg = silu(x W_gate^T + b_gate)   (grid 8 x 64, SPM=4 -> 2 blocks/CU)
    gemm_wres<2, false><<<dim3(512), dim3(256), 0, stream>>>(
        x_bf, Wg_bf, (const bf16_t*)nullptr, (const bf16_t*)nullptr,
        b_gate, (void*)xg_bf, 16384, 4);
    // s = xg W_sp^T + b_sp
    gemm_wres<1, false><<<dim3(512), dim3(256), 0, stream>>>(
        xg_bf, Wsp_bf, (const bf16_t*)nullptr, (const bf16_t*)nullptr,
        b_sp, (void*)s_bf, 16384, 4);

    scan_partial<<<dim3(512), dim3(256), 0, stream>>>(s_bf, decay, carry);
    scan_carry<<<dim3(8), dim3(256), 0, stream>>>(carry, decay, state0, exc, out + 8388608);
    scan_final<<<dim3(512), dim3(256), 0, stream>>>(s_bf, decay, exc, states);

    // out = states WcT^T + xg W2^T + b_out   (both panels resident, grid 8 x 32, SPM=8)
    gemm_wres<0, true><<<dim3(256), dim3(256), 0, stream>>>(
        states, WcT_bf, xg_bf, W2_bf, b_out, (void*)out, 16384, 8);
}

// Round 9
// 133.467 us; speedup vs baseline: 2.4135x; 2.4135x over previous
//
#include <hip/hip_runtime.h>
#include <hip/hip_bf16.h>
#include <stdint.h>

// SSMBlock: x -> silu(x Wg^T) -> s = xg Wsp^T -> scan(decay) -> out = states WcT^T + xg W2^T + b_out
// R8 GEMM: catalog 2-phase minimum (T3 recipe, m230/m248): double-buffered LDS,
// STAGE(t+1) issued BEFORE compute(t), ONE __syncthreads per K-tile. 128x128 tile,
// BK=64, 8 iters (NT=8; concat-K NT=16 for the final dual GEMM). K=512 fixed.

typedef __bf16 bf16_t;
typedef bf16_t bf16x8 __attribute__((ext_vector_type(8)));
typedef bf16_t bf16x4 __attribute__((ext_vector_type(4)));
typedef float  f32x4  __attribute__((ext_vector_type(4)));

static __device__ __forceinline__ void async_copy16(bf16_t* lds, const bf16_t* g) {
    __builtin_amdgcn_global_load_lds((const __attribute__((address_space(1))) void*)g,
                                     (__attribute__((address_space(3))) void*)lds, 16, 0, 0);
}

// Block 256 thr / 4 waves (2x2); wave tile 64x64; acc 4x4 f32x4.
// LDS per buf: [kcomb(8)][row(128)][8] for A and B (16 KB each) -> gll dest linear in
// lane order (chunk c = kcomb*128+row, byte = c*16); ds_read_b128 per 16-lane group =
// contiguous 256B -> 0 bank conflicts (measured 0 in R0-R7).
// Loop (catalog T3 minimum): stage(t+1); ds_read(t); MFMA(t); __syncthreads.
// Hazard: reads of buf[t&1] finish before barrier; t+1 stages into buf[t&1]^... i.e.
// buf[(t+1)&1^1] = buf[t&1] only AFTER that barrier. Single barrier per tile.
// MODE: 0 = f32 out (+bias), 1 = bf16 out (+bias), 2 = silu -> bf16 (+bias)
template <int MODE, int NT>
__global__ __launch_bounds__(256, 2) void gemm_2ph(
    const bf16_t* __restrict__ A0, const bf16_t* __restrict__ W0,
    const bf16_t* __restrict__ A1, const bf16_t* __restrict__ W1,
    const float* __restrict__ bias, void* __restrict__ outp, int M)
{
    constexpr int K = 512;
    __shared__ bf16_t As[2][8 * 128 * 8];   // 2 x 16 KB
    __shared__ bf16_t Bs[2][8 * 128 * 8];   // 2 x 16 KB
    const int tid = threadIdx.x;
    int bid = blockIdx.x;
    {   // XCD-chunked swizzle (bijective: grids are %8==0): XCD x gets a contiguous
        // run of logical tiles -> the 4 n-blocks of an m-panel share one XCD's L2.
        int nwg = gridDim.x;
        if ((nwg & 7) == 0) bid = (bid & 7) * (nwg >> 3) + (bid >> 3);
    }
    const int m0 = (bid >> 2) << 7, n0 = (bid & 3) << 7;   // tN = 512/128 = 4
    const int l = tid & 63, w = tid >> 6;
    const int wr = w >> 1, wc = w & 1;
    const int lr = l & 15, kc = l >> 4;

    float bv[4];
    #pragma unroll
    for (int j = 0; j < 4; ++j)
        bv[j] = bias ? bias[n0 + wc * 64 + j * 16 + lr] : 0.f;

    f32x4 acc[4][4];
    const f32x4 z = {0.f, 0.f, 0.f, 0.f};
    #pragma unroll
    for (int i = 0; i < 4; ++i)
        #pragma unroll
        for (int j = 0; j < 4; ++j) acc[i][j] = z;

    // stage K-tile t (64 k-columns) into buf[t&1]: 1024 chunks each for A and B,
    // 4 chunks/thread each; chunk c = j*256 + tid -> kcomb = c>>7, row = c&127.
    auto stage = [&](int t) {
        const bf16_t* __restrict__ Asrc = (t < 8) ? A0 : A1;
        const bf16_t* __restrict__ Wsrc = (t < 8) ? W0 : W1;
        const int kk = (t & 7) << 6;
        bf16_t* bufA = As[t & 1];
        bf16_t* bufB = Bs[t & 1];
        #pragma unroll
        for (int j = 0; j < 4; ++j) {
            const int c = j * 256 + tid;
            const int row = c & 127, kcomb = c >> 7;
            async_copy16(bufA + (j * 256 + w * 64) * 8,
                         Asrc + (size_t)(m0 + row) * K + kk + kcomb * 8);
            async_copy16(bufB + (j * 256 + w * 64) * 8,
                         Wsrc + (size_t)(n0 + row) * K + kk + kcomb * 8);
        }
    };

    stage(0);
    __syncthreads();                        // buf0 ready (drains vmcnt)

    #pragma unroll
    for (int t = 0; t < NT; ++t) {
        if (t + 1 < NT) stage(t + 1);       // prefetch next tile FIRST (T3 recipe)
        const bf16_t* __restrict__ bufA = As[t & 1];
        const bf16_t* __restrict__ bufB = Bs[t & 1];
        bf16x8 a[2][4], b[2][4];            // [ks][frag]
        #pragma unroll
        for (int ks = 0; ks < 2; ++ks) {
            #pragma unroll
            for (int i = 0; i < 4; ++i)
                a[ks][i] = *(const bf16x8*)(bufA + ((ks * 4 + kc) * 128 + wr * 64 + i * 16 + lr) * 8);
            #pragma unroll
            for (int j = 0; j < 4; ++j)
                b[ks][j] = *(const bf16x8*)(bufB + ((ks * 4 + kc) * 128 + wc * 64 + j * 16 + lr) * 8);
        }
        #pragma unroll
        for (int ks = 0; ks < 2; ++ks)
            #pragma unroll
            for (int i = 0; i < 4; ++i)
                #pragma unroll
                for (int j = 0; j < 4; ++j)
                    acc[i][j] = __builtin_amdgcn_mfma_f32_16x16x32_bf16(
                        a[ks][i], b[ks][j], acc[i][j], 0, 0, 0);
        if (t + 1 < NT) __syncthreads();    // next buf staged + this buf's reads done
    }

    // C/D layout: col = lane&15, row = (lane>>4)*4 + reg   [verified R0]
    float*  outF = (float*)outp;
    bf16_t* outB = (bf16_t*)outp;
    #pragma unroll
    for (int i = 0; i < 4; ++i) {
        const int row = m0 + wr * 64 + i * 16 + kc * 4;
        #pragma unroll
        for (int j = 0; j < 4; ++j) {
            const int col = n0 + wc * 64 + j * 16 + lr;
            #pragma unroll
            for (int r = 0; r < 4; ++r) {
                float v = acc[i][j][r] + bv[j];
                size_t idx = (size_t)(row + r) * 512 + col;
                if (MODE == 0)      outF[idx] = v;
                else if (MODE == 1) outB[idx] = (bf16_t)v;
                else { outB[idx] = (bf16_t)(v / (1.f + __expf(-v))); }
            }
        }
    }
}

// fused prep: x->bf16 (all 8192 blocks), weight prep (blocks<1024), decay (blocks<128)
__global__ void prep_all(const float4* __restrict__ x, bf16x4* __restrict__ xb,
                         const float* __restrict__ Wg, const float* __restrict__ Wsp,
                         const float* __restrict__ Wo, const float* __restrict__ Dp,
                         bf16_t* __restrict__ Wg_bf, bf16_t* __restrict__ Wsp_bf,
                         bf16_t* __restrict__ Wo_bf, bf16_t* __restrict__ W2_bf,
                         const float* __restrict__ A_log, float* __restrict__ decay)
{
    const int blk = blockIdx.x, tid = threadIdx.x;
    {   // x -> bf16, 4 floats/thread
        int i = blk * 256 + tid;
        float4 v = x[i];
        bf16x4 o;
        o[0] = (bf16_t)v.x; o[1] = (bf16_t)v.y; o[2] = (bf16_t)v.z; o[3] = (bf16_t)v.w;
        xb[i] = o;
    }
    if (blk < 1024) {
        int i = blk * 256 + tid;          // 512*512 elements
        Wg_bf[i]  = (bf16_t)Wg[i];
        Wsp_bf[i] = (bf16_t)Wsp[i];
        float wo  = Wo[i];
        Wo_bf[i]  = (bf16_t)wo;
        W2_bf[i]  = (bf16_t)(wo * Dp[i & 511]);   // W2[d',d] = W_out[d',d]*D[d]
    }
    if (blk < 128) {
        int d = blk * 4 + (tid >> 6);     // one wave per row of A_log
        int ll = tid & 63;
        const float* row = A_log + (size_t)d * 512;
        float s = 0.f;
        for (int k = ll; k < 512; k += 64) s += expf(row[k]);
        #pragma unroll
        for (int off = 32; off > 0; off >>= 1) s += __shfl_down(s, off);
        if (ll == 0) decay[d] = expf(-s * (1.f / 512.f));  // exp(mean(-exp(A_log)))
    }
}

// ---- chunked scan: S=4096 -> 64 chunks x 64 steps, per (b,n) lane ----
__global__ void scan_partial(const bf16_t* __restrict__ s, const float* __restrict__ decay,
                             float* __restrict__ carry)
{
    int g = blockIdx.x * 256 + threadIdx.x;       // B*N*64 = 131072
    int n = g & 511, ch = (g >> 9) & 63, b = g >> 15;
    float dec = decay[n];
    const bf16_t* sp = s + (size_t)(b * 4096 + ch * 64) * 512 + n;
    float st = 0.f;
    #pragma unroll 8
    for (int i = 0; i < 64; ++i) st = st * dec + (float)sp[(size_t)i * 512];
    carry[(size_t)(b * 64 + ch) * 512 + n] = st;
}

__global__ void scan_carry(const float* __restrict__ carry, const float* __restrict__ decay,
                           const float* __restrict__ state0,
                           float* __restrict__ exc, float* __restrict__ state_f)
{
    int g = blockIdx.x * 256 + threadIdx.x;       // B*N = 2048
    int n = g & 511, b = g >> 9;
    float dec = decay[n];
    float d64 = dec;
    #pragma unroll
    for (int t = 0; t < 6; ++t) d64 *= d64;       // dec^64 via squaring
    float st = state0[g];
    for (int ch = 0; ch < 64; ++ch) {
        size_t idx = (size_t)(b * 64 + ch) * 512 + n;
        exc[idx] = st;                             // exclusive carry-in per chunk
        st = st * d64 + carry[idx];
    }
    state_f[g] = st;                               // final state -> d_out tail
}

__global__ void scan_final(const bf16_t* __restrict__ s, const float* __restrict__ decay,
                           const float* __restrict__ exc, bf16_t* __restrict__ states)
{
    int g = blockIdx.x * 256 + threadIdx.x;       // B*N*64
    int n = g & 511, ch = (g >> 9) & 63, b = g >> 15;
    float dec = decay[n];
    float st = exc[(size_t)(b * 64 + ch) * 512 + n];
    size_t base = (size_t)(b * 4096 + ch * 64) * 512 + n;
    #pragma unroll 8
    for (int i = 0; i < 64; ++i) {
        st = st * dec + (float)s[base + (size_t)i * 512];
        states[base + (size_t)i * 512] = (bf16_t)st;
    }
}

extern "C" void kernel_launch(void* const* d_in, const int* in_sizes, int n_in,
                              void* d_out, int out_size, void* d_ws, size_t ws_size,
                              hipStream_t stream)
{
    const float* x      = (const float*)d_in[0];
    const float* state0 = (const float*)d_in[1];
    const float* W_gate = (const float*)d_in[2];
    const float* b_gate = (const float*)d_in[3];
    const float* W_sp   = (const float*)d_in[4];
    const float* b_sp   = (const float*)d_in[5];
    const float* W_out  = (const float*)d_in[6];
    const float* b_out  = (const float*)d_in[7];
    const float* A_log  = (const float*)d_in[8];
    const float* D_par  = (const float*)d_in[9];
    float* out = (float*)d_out;

    // workspace layout (~51.5 MB)
    char* ws = (char*)d_ws;
    bf16_t* x_bf   = (bf16_t*)ws;                     // 16 MB, reused for states
    bf16_t* states = x_bf;
    bf16_t* xg_bf  = (bf16_t*)(ws + (16u << 20));     // 16 MB
    bf16_t* s_bf   = (bf16_t*)(ws + (32u << 20));     // 16 MB
    bf16_t* Wg_bf  = (bf16_t*)(ws + (48u << 20));     // 5 x 512 KB weights
    bf16_t* Wsp_bf = Wg_bf + 262144;
    bf16_t* Wo_bf  = Wg_bf + 2 * 262144;
    bf16_t* W2_bf  = Wg_bf + 3 * 262144;
    bf16_t* WcT_bf = Wg_bf + 4 * 262144;
    float*  carry  = (float*)(Wg_bf + 5 * 262144);    // 512 KB
    float*  exc    = carry + 131072;                  // 512 KB
    float*  decay  = exc + 131072;                    // 2 KB

    prep_all<<<dim3(8192), dim3(256), 0, stream>>>(
        (const float4*)x, (bf16x4*)x_bf, W_gate, W_sp, W_out, D_par,
        Wg_bf, Wsp_bf, Wo_bf, W2_bf, A_log, decay);

    // WcT[d',n] = sum_d W_out[d',d] * W_sp[n,d]   (M=512 -> grid 4x4 = 16)
    gemm_2ph<1, 8><<<dim3(16), dim3(256), 0, stream>>>(
        Wo_bf, Wsp_bf, (const bf16_t*)nullptr, (const bf16_t*)nullptr,
        (const float*)nullptr, (void*)WcT_bf, 512);
    // xg = silu(x W_gate^T + b_gate)   (grid 128x4 = 512 -> 2 blocks/CU)
    gemm_2ph<2, 8><<<dim3(512), dim3(256), 0, stream>>>(
        x_bf, Wg_bf, (const bf16_t*)nullptr, (const bf16_t*)nullptr,
        b_gate, (void*)xg_bf, 16384);
    // s = xg W_sp^T + b_sp
    gemm_2ph<1, 8><<<dim3(512), dim3(256), 0, stream>>>(
        xg_bf, Wsp_bf, (const bf16_t*)nullptr, (const bf16_t*)nullptr,
        b_sp, (void*)s_bf, 16384);

    scan_partial<<<dim3(512), dim3(256), 0, stream>>>(s_bf, decay, carry);
    scan_carry<<<dim3(8), dim3(256), 0, stream>>>(carry, decay, state0, exc, out + 8388608);
    scan_final<<<dim3(512), dim3(256), 0, stream>>>(s_bf, decay, exc, states);

    // out = states WcT^T + xg W2^T + b_out   (concat-K, NT=16)
    gemm_2ph<0, 16><<<dim3(512), dim3(256), 0, stream>>>(
        states, WcT_bf, xg_bf, W2_bf, b_out, (void*)out, 16384);
}

// Round 10
// 96.693 us; speedup vs baseline: 3.3313x; 1.3803x over previous
//
#include <hip/hip_runtime.h>
#include <hip/hip_bf16.h>
#include <stdint.h>

// SSMBlock: x -> silu(x Wg^T) -> s = xg Wsp^T -> scan(decay) -> out = states WcT^T + xg W2^T + b_out
// R9 GEMM: R8's 2-phase skeleton + COALESCED staging. LDS tiles are row-major [128][64]
// bf16 with chunk-XOR swizzle (phys_chunk16 = k_chunk ^ (row&7)); global_load_lds source
// is pre-swizzled per-lane (rule #21 both-sides): each gll reads a 1KB window = 8 FULL
// cachelines (was: 64 lines x 16B gather). bf16 epilogue goes through LDS -> 16B/lane
// coalesced stores (was: 2B scattered, 2x WRITE inflation).

typedef __bf16 bf16_t;
typedef bf16_t bf16x8 __attribute__((ext_vector_type(8)));
typedef bf16_t bf16x4 __attribute__((ext_vector_type(4)));
typedef float  f32x4  __attribute__((ext_vector_type(4)));

static __device__ __forceinline__ void async_copy16(bf16_t* lds, const bf16_t* g) {
    __builtin_amdgcn_global_load_lds((const __attribute__((address_space(1))) void*)g,
                                     (__attribute__((address_space(3))) void*)lds, 16, 0, 0);
}

// Block 256 thr / 4 waves (2x2); tile 128x128, BK=64, wave tile 64x64, acc 4x4 f32x4.
// LDS per buf: [row(128)][k(64)] bf16, 16 KB; phys byte = row*128 + (chunk ^ (row&7))*16.
// Stage: wave w, v=0..3 -> window win=w*4+v (rows win*8..+7, 1KB). Lane l: row_local=l>>3,
// phys chunk l&7 -> source k-chunk sc=(l&7)^(l>>3); dest = buf + win*512 (+ lane*16 by HW).
// Frag read: a = buf + row*64 + (((ks*4+kc)^(lr&7))<<3), row = wr*64+i*16+lr. Bank-audit:
// per instr 8 lanes/16B-slot with 8 distinct rows = 8 rounds = b128 floor (conflict-free).
// Loop: stage(t+1) FIRST; ds_read(t); MFMA(t); one __syncthreads per tile (T3 minimum).
// MODE: 0 = f32 out (+bias), 1 = bf16 out (+bias), 2 = silu -> bf16 (+bias)
template <int MODE, int NT>
__global__ __launch_bounds__(256, 2) void gemm_2ph(
    const bf16_t* __restrict__ A0, const bf16_t* __restrict__ W0,
    const bf16_t* __restrict__ A1, const bf16_t* __restrict__ W1,
    const float* __restrict__ bias, void* __restrict__ outp, int M)
{
    constexpr int K = 512;
    __shared__ bf16_t As[2][128 * 64];   // 2 x 16 KB
    __shared__ bf16_t Bs[2][128 * 64];   // 2 x 16 KB
    const int tid = threadIdx.x;
    int bid = blockIdx.x;
    {   // XCD-chunked swizzle (grids are %8==0)
        int nwg = gridDim.x;
        if ((nwg & 7) == 0) bid = (bid & 7) * (nwg >> 3) + (bid >> 3);
    }
    const int m0 = (bid >> 2) << 7, n0 = (bid & 3) << 7;   // tN = 512/128 = 4
    const int l = tid & 63, w = tid >> 6;
    const int wr = w >> 1, wc = w & 1;
    const int lr = l & 15, kc = l >> 4;
    const int rloc = l >> 3, sc = (l & 7) ^ rloc;          // staging source permutation

    float bv[4];
    #pragma unroll
    for (int j = 0; j < 4; ++j)
        bv[j] = bias ? bias[n0 + wc * 64 + j * 16 + lr] : 0.f;

    f32x4 acc[4][4];
    const f32x4 z = {0.f, 0.f, 0.f, 0.f};
    #pragma unroll
    for (int i = 0; i < 4; ++i)
        #pragma unroll
        for (int j = 0; j < 4; ++j) acc[i][j] = z;

    // stage K-tile t (64 k-cols) into buf[t&1]: 16 windows of 1KB; wave w owns 4.
    auto stage = [&](int t) {
        const bf16_t* __restrict__ Asrc = (t < 8) ? A0 : A1;
        const bf16_t* __restrict__ Wsrc = (t < 8) ? W0 : W1;
        const int kk = (t & 7) << 6;
        bf16_t* bufA = As[t & 1];
        bf16_t* bufB = Bs[t & 1];
        #pragma unroll
        for (int v = 0; v < 4; ++v) {
            const int win = w * 4 + v;          // rows win*8 .. win*8+7
            async_copy16(bufA + win * 512,      // wave-uniform base; HW adds lane*16
                         Asrc + (size_t)(m0 + win * 8 + rloc) * K + kk + sc * 8);
            async_copy16(bufB + win * 512,
                         Wsrc + (size_t)(n0 + win * 8 + rloc) * K + kk + sc * 8);
        }
    };

    stage(0);
    __syncthreads();                        // buf0 ready (drains vmcnt)

    #pragma unroll
    for (int t = 0; t < NT; ++t) {
        if (t + 1 < NT) stage(t + 1);       // prefetch next tile FIRST
        const bf16_t* __restrict__ bufA = As[t & 1];
        const bf16_t* __restrict__ bufB = Bs[t & 1];
        bf16x8 a[2][4], b[2][4];            // [ks][frag]
        #pragma unroll
        for (int ks = 0; ks < 2; ++ks) {
            #pragma unroll
            for (int i = 0; i < 4; ++i)
                a[ks][i] = *(const bf16x8*)(bufA + (wr * 64 + i * 16 + lr) * 64
                                            + (((ks * 4 + kc) ^ (lr & 7)) << 3));
            #pragma unroll
            for (int j = 0; j < 4; ++j)
                b[ks][j] = *(const bf16x8*)(bufB + (wc * 64 + j * 16 + lr) * 64
                                            + (((ks * 4 + kc) ^ (lr & 7)) << 3));
        }
        #pragma unroll
        for (int ks = 0; ks < 2; ++ks)
            #pragma unroll
            for (int i = 0; i < 4; ++i)
                #pragma unroll
                for (int j = 0; j < 4; ++j)
                    acc[i][j] = __builtin_amdgcn_mfma_f32_16x16x32_bf16(
                        a[ks][i], b[ks][j], acc[i][j], 0, 0, 0);
        if (t + 1 < NT) __syncthreads();    // next buf staged + this buf's reads done
    }

    // C/D layout: col = lane&15, row = (lane>>4)*4 + reg   [verified R0]
    if (MODE == 0) {
        float* outF = (float*)outp;         // f32: 64B/16-lane-group, already coalesced
        #pragma unroll
        for (int i = 0; i < 4; ++i) {
            const int row = m0 + wr * 64 + i * 16 + kc * 4;
            #pragma unroll
            for (int j = 0; j < 4; ++j) {
                const int col = n0 + wc * 64 + j * 16 + lr;
                #pragma unroll
                for (int r = 0; r < 4; ++r)
                    outF[(size_t)(row + r) * 512 + col] = acc[i][j][r] + bv[j];
            }
        }
    } else {
        // bf16: repack via LDS (reuse As = 32 KB), then 16B/lane coalesced stores
        __syncthreads();                    // all waves done with K-loop LDS
        bf16_t* eps = &As[0][0];            // 128 x 128 bf16 = 32 KB
        #pragma unroll
        for (int i = 0; i < 4; ++i) {
            const int row = wr * 64 + i * 16 + kc * 4;
            #pragma unroll
            for (int j = 0; j < 4; ++j) {
                const int col = wc * 64 + j * 16 + lr;
                #pragma unroll
                for (int r = 0; r < 4; ++r) {
                    float v = acc[i][j][r] + bv[j];
                    if (MODE == 2) v = v / (1.f + __expf(-v));
                    eps[(row + r) * 128 + col] = (bf16_t)v;
                }
            }
        }
        __syncthreads();
        bf16_t* outB = (bf16_t*)outp;
        #pragma unroll
        for (int s2 = 0; s2 < 8; ++s2) {
            const int row = s2 * 16 + (tid >> 4);
            const int col = (tid & 15) * 8;
            *(bf16x8*)(outB + (size_t)(m0 + row) * 512 + n0 + col) =
                *(const bf16x8*)(eps + row * 128 + col);
        }
    }
}

// fused prep: x->bf16 (all 8192 blocks), weight prep (blocks<1024), decay (blocks<128)
__global__ void prep_all(const float4* __restrict__ x, bf16x4* __restrict__ xb,
                         const float* __restrict__ Wg, const float* __restrict__ Wsp,
                         const float* __restrict__ Wo, const float* __restrict__ Dp,
                         bf16_t* __restrict__ Wg_bf, bf16_t* __restrict__ Wsp_bf,
                         bf16_t* __restrict__ Wo_bf, bf16_t* __restrict__ W2_bf,
                         const float* __restrict__ A_log, float* __restrict__ decay)
{
    const int blk = blockIdx.x, tid = threadIdx.x;
    {   // x -> bf16, 4 floats/thread
        int i = blk * 256 + tid;
        float4 v = x[i];
        bf16x4 o;
        o[0] = (bf16_t)v.x; o[1] = (bf16_t)v.y; o[2] = (bf16_t)v.z; o[3] = (bf16_t)v.w;
        xb[i] = o;
    }
    if (blk < 1024) {
        int i = blk * 256 + tid;          // 512*512 elements
        Wg_bf[i]  = (bf16_t)Wg[i];
        Wsp_bf[i] = (bf16_t)Wsp[i];
        float wo  = Wo[i];
        Wo_bf[i]  = (bf16_t)wo;
        W2_bf[i]  = (bf16_t)(wo * Dp[i & 511]);   // W2[d',d] = W_out[d',d]*D[d]
    }
    if (blk < 128) {
        int d = blk * 4 + (tid >> 6);     // one wave per row of A_log
        int ll = tid & 63;
        const float* row = A_log + (size_t)d * 512;
        float s = 0.f;
        for (int k = ll; k < 512; k += 64) s += expf(row[k]);
        #pragma unroll
        for (int off = 32; off > 0; off >>= 1) s += __shfl_down(s, off);
        if (ll == 0) decay[d] = expf(-s * (1.f / 512.f));  // exp(mean(-exp(A_log)))
    }
}

// ---- chunked scan: S=4096 -> 64 chunks x 64 steps, per (b,n) lane ----
__global__ void scan_partial(const bf16_t* __restrict__ s, const float* __restrict__ decay,
                             float* __restrict__ carry)
{
    int g = blockIdx.x * 256 + threadIdx.x;       // B*N*64 = 131072
    int n = g & 511, ch = (g >> 9) & 63, b = g >> 15;
    float dec = decay[n];
    const bf16_t* sp = s + (size_t)(b * 4096 + ch * 64) * 512 + n;
    float st = 0.f;
    #pragma unroll 8
    for (int i = 0; i < 64; ++i) st = st * dec + (float)sp[(size_t)i * 512];
    carry[(size_t)(b * 64 + ch) * 512 + n] = st;
}

__global__ void scan_carry(const float* __restrict__ carry, const float* __restrict__ decay,
                           const float* __restrict__ state0,
                           float* __restrict__ exc, float* __restrict__ state_f)
{
    int g = blockIdx.x * 256 + threadIdx.x;       // B*N = 2048
    int n = g & 511, b = g >> 9;
    float dec = decay[n];
    float d64 = dec;
    #pragma unroll
    for (int t = 0; t < 6; ++t) d64 *= d64;       // dec^64 via squaring
    float st = state0[g];
    for (int ch = 0; ch < 64; ++ch) {
        size_t idx = (size_t)(b * 64 + ch) * 512 + n;
        exc[idx] = st;                             // exclusive carry-in per chunk
        st = st * d64 + carry[idx];
    }
    state_f[g] = st;                               // final state -> d_out tail
}

__global__ void scan_final(const bf16_t* __restrict__ s, const float* __restrict__ decay,
                           const float* __restrict__ exc, bf16_t* __restrict__ states)
{
    int g = blockIdx.x * 256 + threadIdx.x;       // B*N*64
    int n = g & 511, ch = (g >> 9) & 63, b = g >> 15;
    float dec = decay[n];
    float st = exc[(size_t)(b * 64 + ch) * 512 + n];
    size_t base = (size_t)(b * 4096 + ch * 64) * 512 + n;
    #pragma unroll 8
    for (int i = 0; i < 64; ++i) {
        st = st * dec + (float)s[base + (size_t)i * 512];
        states[base + (size_t)i * 512] = (bf16_t)st;
    }
}

extern "C" void kernel_launch(void* const* d_in, const int* in_sizes, int n_in,
                              void* d_out, int out_size, void* d_ws, size_t ws_size,
                              hipStream_t stream)
{
    const float* x      = (const float*)d_in[0];
    const float* state0 = (const float*)d_in[1];
    const float* W_gate = (const float*)d_in[2];
    const float* b_gate = (const float*)d_in[3];
    const float* W_sp   = (const float*)d_in[4];
    const float* b_sp   = (const float*)d_in[5];
    const float* W_out  = (const float*)d_in[6];
    const float* b_out  = (const float*)d_in[7];
    const float* A_log  = (const float*)d_in[8];
    const float* D_par  = (const float*)d_in[9];
    float* out = (float*)d_out;

    // workspace layout (~51.5 MB)
    char* ws = (char*)d_ws;
    bf16_t* x_bf   = (bf16_t*)ws;                     // 16 MB, reused for states
    bf16_t* states = x_bf;
    bf16_t* xg_bf  = (bf16_t*)(ws + (16u << 20));     // 16 MB
    bf16_t* s_bf   = (bf16_t*)(ws + (32u << 20));     // 16 MB
    bf16_t* Wg_bf  = (bf16_t*)(ws + (48u << 20));     // 5 x 512 KB weights
    bf16_t* Wsp_bf = Wg_bf + 262144;
    bf16_t* Wo_bf  = Wg_bf + 2 * 262144;
    bf16_t* W2_bf  = Wg_bf + 3 * 262144;
    bf16_t* WcT_bf = Wg_bf + 4 * 262144;
    float*  carry  = (float*)(Wg_bf + 5 * 262144);    // 512 KB
    float*  exc    = carry + 131072;                  // 512 KB
    float*  decay  = exc + 131072;                    // 2 KB

    prep_all<<<dim3(8192), dim3(256), 0, stream>>>(
        (const float4*)x, (bf16x4*)x_bf, W_gate, W_sp, W_out, D_par,
        Wg_bf, Wsp_bf, Wo_bf, W2_bf, A_log, decay);

    // WcT[d',n] = sum_d W_out[d',d] * W_sp[n,d]   (M=512 -> grid 4x4 = 16)
    gemm_2ph<1, 8><<<dim3(16), dim3(256), 0, stream>>>(
        Wo_bf, Wsp_bf, (const bf16_t*)nullptr, (const bf16_t*)nullptr,
        (const float*)nullptr, (void*)WcT_bf, 512);
    // xg = silu(x W_gate^T + b_gate)   (grid 128x4 = 512 -> 2 blocks/CU)
    gemm_2ph<2, 8><<<dim3(512), dim3(256), 0, stream>>>(
        x_bf, Wg_bf, (const bf16_t*)nullptr, (const bf16_t*)nullptr,
        b_gate, (void*)xg_bf, 16384);
    // s = xg W_sp^T + b_sp
    gemm_2ph<1, 8><<<dim3(512), dim3(256), 0, stream>>>(
        xg_bf, Wsp_bf, (const bf16_t*)nullptr, (const bf16_t*)nullptr,
        b_sp, (void*)s_bf, 16384);

    scan_partial<<<dim3(512), dim3(256), 0, stream>>>(s_bf, decay, carry);
    scan_carry<<<dim3(8), dim3(256), 0, stream>>>(carry, decay, state0, exc, out + 8388608);
    scan_final<<<dim3(512), dim3(256), 0, stream>>>(s_bf, decay, exc, states);

    // out = states WcT^T + xg W2^T + b_out   (concat-K, NT=16)
    gemm_2ph<0, 16><<<dim3(512), dim3(256), 0, stream>>>(
        states, WcT_bf, xg_bf, W2_bf, b_out, (void*)out, 16384);
}